// Round 6
// baseline (294.466 us; speedup 1.0000x reference)
//
#include <hip/hip_runtime.h>

// Problem constants (from reference):
//   D = 8388608 elements, N = M = 1024 (power of two -> mod == AND)
// Outputs concatenated in d_out (float32):
//   [0,      D)      phase_out  (as float)
//   [D,     2D)      mag_out    (as float)
//   [2D,    3D)      signal
//   [3D]             strength   (scalar)
//   [3D+1,  4D+1)    grad_phase   <- section base misaligned by 4B
//   [4D+1,  5D+1)    grad_mag     <- same
//
// Two-kernel design (kept): main writes 5 streams + partials to d_ws;
// 1-block kernel reduces. Fused atomic variant regressed 5x. Never.
//
// Optimization history (main kernel time, inferred via dur - 2 fills):
//  R0  ~87us: 4096 one-shot blocks, regular stores, misaligned f32x8 grads.
//  R1  116us: all-nontemporal. nt defeats L2 write-merging (+130 MB WRITE).
//  R2  107us: nt po/mo/sig only. Still +52 MB. Every nt stream costs.
//  R3  ~88us: 32B-aligned grad stores via slot-shift. NEUTRAL -> alignment
//      was never the problem (no partial-line RMW penalty).
//  R4  ~86us: 2048 persistent blocks x 2 tiles, cross-tile load pipeline.
//      NEUTRAL -> staging amortization / load hoisting not the limiter.
//  R5: all pipes idle (VALU 4.5%, conflicts 0.6%, occ 66%) yet main runs
//      at 3.4 TB/s vs 6.3-6.7 achievable; R1/R2 showed time doesn't track
//      traffic. Last mechanism standing: the end-of-block __syncthreads()
//      compiles to s_waitcnt vmcnt(0) + s_barrier -- every wave waits for
//      ALL 10 output stores to ack before siblings pass; lockstep blocks
//      => periodic CU-wide issue gaps => read-pipe starvation sawtooth.
//      Fix: drop the end barrier. Each wave's lane 0 writes its shfl-tree
//      partial straight to wave_sums[tile*4+wave]; the reduce kernel
//      combines ((w0+w1)+w2)+w3 sequentially -- the EXACT association
//      thread 0 used before -> strength bitwise identical. Fallback to the
//      R4 path if ws_size < 64 KB.
//      (R5 bench attempt died in container acquisition -- "MI355X container
//      failed twice", no compile/run diagnostic. This is an unchanged
//      resubmit; the hypothesis is still untested.)
constexpr int D_TOTAL = 8388608;
constexpr int TBL = 1024;
constexpr int IDX_MASK = 1023;
constexpr int BLOCK = 256;
constexpr int VEC = 8;                              // elements per thread
constexpr int ELEMS_PER_TILE = BLOCK * VEC;         // 2048
constexpr int NTILES = D_TOTAL / ELEMS_PER_TILE;    // 4096 partial tiles
constexpr int TPB = 2;                              // tiles per block
constexpr int NBLOCKS_MAIN = NTILES / TPB;          // 2048
constexpr int WAVES_PER_TILE = BLOCK / 64;          // 4

typedef float f32x4 __attribute__((ext_vector_type(4)));
typedef float f32x8 __attribute__((ext_vector_type(8)));
typedef int   i32x8 __attribute__((ext_vector_type(8)));
// Grad sections start at 3D+1/4D+1 (4B off 32B). aligned(4) f32x8 makes
// clang emit paired global_store_dwordx4 (dword alignment is all HW needs).
// R3 proved alignment-shifting these stores is perf-neutral; keep simple.
typedef f32x8 f32x8u __attribute__((aligned(4)));

__device__ __forceinline__ float process_tile(
    int base, i32x8 cp, i32x8 cm, i32x8 sp, i32x8 sm,
    const float2* __restrict__ s_phase, const float2* __restrict__ s_mag,
    float* __restrict__ out) {
  int p[VEC], m[VEC];
#pragma unroll
  for (int j = 0; j < VEC; ++j) {
    p[j] = (cp[j] + sp[j]) & IDX_MASK;
    m[j] = (cm[j] + sm[j]) & IDX_MASK;
  }
  f32x8 po, mo, sg;
  f32x8u gp, gm;
  float local = 0.f;
  // Accumulation order over j=0..7 IDENTICAL to all verified rounds
  // (strength bitwise-stable, absmax 0.0 five rounds running).
#pragma unroll
  for (int j = 0; j < VEC; ++j) {
    const float2 ph = s_phase[p[j]];
    const float2 mg = s_mag[m[j]];
    const float s = ph.x * mg.x;
    sg[j] = s;
    gp[j] = ph.y * mg.x;
    gm[j] = ph.x * mg.y;
    po[j] = (float)p[j];
    mo[j] = (float)m[j];
    local += s;
  }
  // All regular stores (R1/R2 lesson: nt costs +50..130 MB WRITE_SIZE).
  *reinterpret_cast<f32x8*>(out + base)                     = po;
  *reinterpret_cast<f32x8*>(out + D_TOTAL + base)           = mo;
  *reinterpret_cast<f32x8*>(out + 2 * D_TOTAL + base)       = sg;
  *reinterpret_cast<f32x8u*>(out + 3 * D_TOTAL + 1 + base)  = gp;
  *reinterpret_cast<f32x8u*>(out + 4 * D_TOTAL + 1 + base)  = gm;
  return local;
}

// Shared prologue: issue tile0 loads, stage tables, barrier, issue tile1
// loads. (R4-proven structure; barrier here is cheap -- it hides under the
// tile0 idx-load latency and staging.)
#define PHASECELL_PROLOGUE                                                   \
  const int base0 = (blockIdx.x * TPB) * ELEMS_PER_TILE + threadIdx.x * VEC; \
  const int base1 = base0 + ELEMS_PER_TILE;                                  \
  const i32x8 cp0 = *reinterpret_cast<const i32x8*>(ctx_p + base0);          \
  const i32x8 cm0 = *reinterpret_cast<const i32x8*>(ctx_m + base0);          \
  const i32x8 sp0 = *reinterpret_cast<const i32x8*>(self_p + base0);         \
  const i32x8 sm0 = *reinterpret_cast<const i32x8*>(self_m + base0);         \
  __shared__ float2 s_phase[TBL];                                            \
  __shared__ float2 s_mag[TBL];                                              \
  for (int i = threadIdx.x; i < TBL; i += BLOCK) {                           \
    s_phase[i] = make_float2(cos_t[i], dcos_t[i]);                           \
    s_mag[i]   = make_float2(exp_t[i], dexp_t[i]);                           \
  }                                                                          \
  __syncthreads();                                                           \
  const i32x8 cp1 = *reinterpret_cast<const i32x8*>(ctx_p + base1);          \
  const i32x8 cm1 = *reinterpret_cast<const i32x8*>(ctx_m + base1);          \
  const i32x8 sp1 = *reinterpret_cast<const i32x8*>(self_p + base1);         \
  const i32x8 sm1 = *reinterpret_cast<const i32x8*>(self_m + base1);         \
  const int wave = threadIdx.x >> 6;                                         \
  const int lane = threadIdx.x & 63;

// ---- Preferred path: barrier-free epilogue, per-wave partial sums. ----
__global__ __launch_bounds__(BLOCK) void phasecell_main_ws(
    const int* __restrict__ ctx_p, const int* __restrict__ ctx_m,
    const int* __restrict__ self_p, const int* __restrict__ self_m,
    const float* __restrict__ cos_t, const float* __restrict__ exp_t,
    const float* __restrict__ dcos_t, const float* __restrict__ dexp_t,
    float* __restrict__ out, float* __restrict__ wave_sums) {
  PHASECELL_PROLOGUE

  float r0 = process_tile(base0, cp0, cm0, sp0, sm0, s_phase, s_mag, out);
#pragma unroll
  for (int off = 32; off > 0; off >>= 1) r0 += __shfl_down(r0, off, 64);
  if (lane == 0)
    wave_sums[(blockIdx.x * TPB + 0) * WAVES_PER_TILE + wave] = r0;

  float r1 = process_tile(base1, cp1, cm1, sp1, sm1, s_phase, s_mag, out);
#pragma unroll
  for (int off = 32; off > 0; off >>= 1) r1 += __shfl_down(r1, off, 64);
  if (lane == 0)
    wave_sums[(blockIdx.x * TPB + 1) * WAVES_PER_TILE + wave] = r1;
  // NO end barrier: waves retire independently; no collective vmcnt(0)
  // drain, no CU-wide issue gap while store queues empty.
}

__global__ __launch_bounds__(BLOCK) void phasecell_reduce_ws(
    const float* __restrict__ wave_sums, float* __restrict__ strength_out) {
  float s = 0.f;
  for (int i = threadIdx.x; i < NTILES; i += BLOCK) {
    const f32x4 w =
        *reinterpret_cast<const f32x4*>(wave_sums + i * WAVES_PER_TILE);
    float t = 0.f;
#pragma unroll
    for (int k = 0; k < WAVES_PER_TILE; ++k) t += w[k];  // ((w0+w1)+w2)+w3:
    s += t;  // exact association the old per-block thread-0 loop used
  }
#pragma unroll
  for (int off = 32; off > 0; off >>= 1) s += __shfl_down(s, off, 64);
  __shared__ float wsum[BLOCK / 64];
  const int wave = threadIdx.x >> 6;
  const int lane = threadIdx.x & 63;
  if (lane == 0) wsum[wave] = s;
  __syncthreads();
  if (threadIdx.x == 0) {
    float t = 0.f;
#pragma unroll
    for (int w = 0; w < BLOCK / 64; ++w) t += wsum[w];
    strength_out[0] = t;  // out[3D]
  }
}

// ---- Fallback path (ws_size < 64 KB): R4 structure verbatim. ----
__global__ __launch_bounds__(BLOCK) void phasecell_main_bs(
    const int* __restrict__ ctx_p, const int* __restrict__ ctx_m,
    const int* __restrict__ self_p, const int* __restrict__ self_m,
    const float* __restrict__ cos_t, const float* __restrict__ exp_t,
    const float* __restrict__ dcos_t, const float* __restrict__ dexp_t,
    float* __restrict__ out, float* __restrict__ block_sums) {
  PHASECELL_PROLOGUE

  __shared__ float wsum[TPB][BLOCK / 64];
  float r0 = process_tile(base0, cp0, cm0, sp0, sm0, s_phase, s_mag, out);
#pragma unroll
  for (int off = 32; off > 0; off >>= 1) r0 += __shfl_down(r0, off, 64);
  if (lane == 0) wsum[0][wave] = r0;

  float r1 = process_tile(base1, cp1, cm1, sp1, sm1, s_phase, s_mag, out);
#pragma unroll
  for (int off = 32; off > 0; off >>= 1) r1 += __shfl_down(r1, off, 64);
  if (lane == 0) wsum[1][wave] = r1;

  __syncthreads();
  if (threadIdx.x == 0) {
    float t0 = 0.f, t1 = 0.f;
#pragma unroll
    for (int w = 0; w < BLOCK / 64; ++w) t0 += wsum[0][w];
#pragma unroll
    for (int w = 0; w < BLOCK / 64; ++w) t1 += wsum[1][w];
    block_sums[blockIdx.x * TPB]     = t0;
    block_sums[blockIdx.x * TPB + 1] = t1;
  }
}

__global__ __launch_bounds__(BLOCK) void phasecell_reduce_bs(
    const float* __restrict__ partials, float* __restrict__ strength_out) {
  float s = 0.f;
  for (int i = threadIdx.x; i < NTILES; i += BLOCK) s += partials[i];
#pragma unroll
  for (int off = 32; off > 0; off >>= 1) s += __shfl_down(s, off, 64);
  __shared__ float wsum[BLOCK / 64];
  const int wave = threadIdx.x >> 6;
  const int lane = threadIdx.x & 63;
  if (lane == 0) wsum[wave] = s;
  __syncthreads();
  if (threadIdx.x == 0) {
    float t = 0.f;
#pragma unroll
    for (int w = 0; w < BLOCK / 64; ++w) t += wsum[w];
    strength_out[0] = t;  // out[3D]
  }
}

extern "C" void kernel_launch(void* const* d_in, const int* in_sizes, int n_in,
                              void* d_out, int out_size, void* d_ws, size_t ws_size,
                              hipStream_t stream) {
  const int* ctx_p  = (const int*)d_in[0];
  const int* ctx_m  = (const int*)d_in[1];
  const int* self_p = (const int*)d_in[2];
  const int* self_m = (const int*)d_in[3];
  const float* cos_t  = (const float*)d_in[4];
  const float* exp_t  = (const float*)d_in[5];
  const float* dcos_t = (const float*)d_in[6];
  const float* dexp_t = (const float*)d_in[7];
  float* out = (float*)d_out;
  float* ws = (float*)d_ws;

  if (ws_size >= (size_t)NTILES * WAVES_PER_TILE * sizeof(float)) {
    phasecell_main_ws<<<NBLOCKS_MAIN, BLOCK, 0, stream>>>(
        ctx_p, ctx_m, self_p, self_m, cos_t, exp_t, dcos_t, dexp_t, out, ws);
    phasecell_reduce_ws<<<1, BLOCK, 0, stream>>>(ws, out + 3 * (size_t)D_TOTAL);
  } else {
    phasecell_main_bs<<<NBLOCKS_MAIN, BLOCK, 0, stream>>>(
        ctx_p, ctx_m, self_p, self_m, cos_t, exp_t, dcos_t, dexp_t, out, ws);
    phasecell_reduce_bs<<<1, BLOCK, 0, stream>>>(ws, out + 3 * (size_t)D_TOTAL);
  }
}